// Round 2
// baseline (265.400 us; speedup 1.0000x reference)
//
#include <hip/hip_runtime.h>

#define M_DIM 2048
#define K_DIM 4096
#define N_DIM 4096
#define KTILES (K_DIM / 64)

typedef unsigned short u16;
typedef unsigned int u32;
typedef __bf16 bf16x8 __attribute__((ext_vector_type(8)));
typedef float f32x4 __attribute__((ext_vector_type(4)));
typedef float f4 __attribute__((ext_vector_type(4)));
typedef u16 u16x8 __attribute__((ext_vector_type(8)));
typedef u32 u32x4 __attribute__((ext_vector_type(4)));

// fp32 -> bf16 round-to-nearest-even
__device__ __forceinline__ u16 f2bf(float f) {
    unsigned int u = __float_as_uint(f);
    u += 0x7fffu + ((u >> 16) & 1u);
    return (u16)(u >> 16);
}

// pack two fp32 -> (bf16(lo) | bf16(hi)<<16), RNE
__device__ __forceinline__ u32 pack2(float lo, float hi) {
    u32 a = __float_as_uint(lo); a += 0x7fffu + ((a >> 16) & 1u);
    u32 b = __float_as_uint(hi); b += 0x7fffu + ((b >> 16) & 1u);
    return (a >> 16) | (b & 0xffff0000u);
}

// async global->LDS, 16B per lane. LDS dest must be wave-uniform base + lane*16.
__device__ __forceinline__ void load16(const void* g, void* l) {
    __builtin_amdgcn_global_load_lds(
        (__attribute__((address_space(1))) const void*)g,
        (__attribute__((address_space(3))) void*)l,
        16, 0, 0);
}

// --------------- fused prep: LDS-free transpose + x->bf16 (UNCHANGED) -------
__global__ __launch_bounds__(256) void prep(const float* __restrict__ x,
                                            u16* __restrict__ xb,
                                            const float* __restrict__ W,
                                            const float* __restrict__ Msk,
                                            u16* __restrict__ Bt) {
    const int t = threadIdx.x;
    if (blockIdx.x >= 2048) {
        // ---- conv_x: 16 floats/thread ----
        size_t i = ((size_t)(blockIdx.x - 2048) * 256 + t) * 16;
#pragma unroll
        for (int h = 0; h < 2; ++h) {
            f4 v0 = *(const f4*)(x + i + h * 8);
            f4 v1 = *(const f4*)(x + i + h * 8 + 4);
            u16x8 o;
            o[0] = f2bf(v0[0]); o[1] = f2bf(v0[1]); o[2] = f2bf(v0[2]); o[3] = f2bf(v0[3]);
            o[4] = f2bf(v1[0]); o[5] = f2bf(v1[1]); o[6] = f2bf(v1[2]); o[7] = f2bf(v1[3]);
            *(u16x8*)(xb + i + h * 8) = o;
        }
        return;
    }
    const int n0 = (blockIdx.x & 31) * 128;         // 32 n-tiles of 128
    const int k0 = (blockIdx.x >> 5) * 64;          // 64 k-tiles of 64
    const int ko = t & 7;                           // k-octet within tile
    const int ng = t >> 3;                          // n-group (4 cols), 0..31

    const float* Wp = W   + (size_t)(k0 + 8 * ko) * N_DIM + n0 + 4 * ng;
    const float* Mp = Msk + (size_t)(k0 + 8 * ko) * N_DIM + n0 + 4 * ng;

    f4 a[8];
#pragma unroll
    for (int j = 0; j < 8; ++j) {
        f4 wv = *(const f4*)(Wp + (size_t)j * N_DIM);
        f4 mv = *(const f4*)(Mp + (size_t)j * N_DIM);
        a[j][0] = mv[0] != 0.f ? wv[0] : 0.f;
        a[j][1] = mv[1] != 0.f ? wv[1] : 0.f;
        a[j][2] = mv[2] != 0.f ? wv[2] : 0.f;
        a[j][3] = mv[3] != 0.f ? wv[3] : 0.f;
    }

    u16* bp = Bt + (size_t)(n0 + 4 * ng) * K_DIM + k0 + 8 * ko;
#pragma unroll
    for (int i = 0; i < 4; ++i) {                   // n within the float4
        u32x4 o;
        o[0] = pack2(a[0][i], a[1][i]);
        o[1] = pack2(a[2][i], a[3][i]);
        o[2] = pack2(a[4][i], a[5][i]);
        o[3] = pack2(a[6][i], a[7][i]);
        *(u32x4*)(bp + (size_t)i * K_DIM) = o;
    }
}

// ---------------- gemm8: 128m x 256n tile, 4-phase counted-vmcnt ------------
// 512 threads = 8 waves (2m x 4n), per-wave 64x64 output. LDS double-buffered
// (96 KB -> 1 WG/CU, grid 16x16 = 256 WGs = exactly 1/CU). Staging of tile
// t+1 split into 3 units {A, B0, B1} x 2 global_load_lds, issued in phases
// 0/1/2 of tile t. Counted waits: vmcnt(2) at ph0 (A(t),B0(t) ready; B1(t)
// in flight) and vmcnt(2) at ph1 (B1(t) ready; A(t+1) in flight) — loads
// never drain, the m97-structure's ~20% barrier-drain stall is removed.
// lgkmcnt(0) before each raw s_barrier closes the cross-wave
// ds_read-in-flight vs next-tile gload_lds overwrite race. Swizzle, fragment
// layout, MFMA orientation and accumulation order identical to the verified
// 128x128 kernel.
__global__ __launch_bounds__(512, 2) void gemm8(const u16* __restrict__ A,   // M x K bf16
                                                const u16* __restrict__ Bt,  // N x K bf16
                                                const float* __restrict__ bias,
                                                float* __restrict__ C) {
    __shared__ __align__(16) u16 As[2][128 * 64];   // 2 x 16 KB
    __shared__ __align__(16) u16 Bs[2][256 * 64];   // 2 x 32 KB

    const int t  = threadIdx.x;
    const int bn = blockIdx.x;      // N / 256
    const int bm = blockIdx.y;      // M / 128

    // staging: row = p*64 + (t>>3), phys chunk = t&7, pre-swizzled source
    // chunk = (t&7) ^ (row&7)  (row&7 == srow&7 since p*64 is a mult of 8)
    const int srow   = t >> 3;
    const int schunk = (t & 7) ^ (srow & 7);
    const u16* gA = A  + (size_t)(bm * 128 + srow) * K_DIM + schunk * 8;
    const u16* gB = Bt + (size_t)(bn * 256 + srow) * K_DIM + schunk * 8;

    const int lane = t & 63;
    const int wv   = t >> 6;
    const int wm = (wv >> 2) * 64;      // wave m-origin within A-tile (0/64)
    const int wn = (wv & 3) * 64;       // wave n-origin within B-tile (0..192)
    const int fr = lane & 15;
    const int q  = lane >> 4;
    const int sw = fr & 7;
    const int col0 = ((0 + q) ^ sw) * 8;    // kk = 0
    const int col1 = ((4 + q) ^ sw) * 8;    // kk = 32

#define STAGE_A(buf, kt) do { \
    load16(gA + (size_t)(kt) * 64,               (buf) + t * 8); \
    load16(gA + (size_t)(kt) * 64 + 64 * K_DIM,  (buf) + 4096 + t * 8); } while (0)
#define STAGE_B0(buf, kt) do { \
    load16(gB + (size_t)(kt) * 64,               (buf) + t * 8); \
    load16(gB + (size_t)(kt) * 64 + 64 * K_DIM,  (buf) + 4096 + t * 8); } while (0)
#define STAGE_B1(buf, kt) do { \
    load16(gB + (size_t)(kt) * 64 + 128 * K_DIM, (buf) + 8192 + t * 8); \
    load16(gB + (size_t)(kt) * 64 + 192 * K_DIM, (buf) + 12288 + t * 8); } while (0)

#define RD(dst, base, row0) do { \
    dst[0][0] = *(const bf16x8*)((base) + ((row0) + fr) * 64 + col0); \
    dst[0][1] = *(const bf16x8*)((base) + ((row0) + fr) * 64 + col1); \
    dst[1][0] = *(const bf16x8*)((base) + ((row0) + 16 + fr) * 64 + col0); \
    dst[1][1] = *(const bf16x8*)((base) + ((row0) + 16 + fr) * 64 + col1); } while (0)

#define MM(fa, fb, mq, nq) do { \
    __builtin_amdgcn_s_setprio(1); \
    _Pragma("unroll") \
    for (int kx = 0; kx < 2; ++kx) \
      _Pragma("unroll") \
      for (int i2 = 0; i2 < 2; ++i2) \
        _Pragma("unroll") \
        for (int j2 = 0; j2 < 2; ++j2) \
          acc[(mq) * 2 + i2][(nq) * 2 + j2] = __builtin_amdgcn_mfma_f32_16x16x32_bf16( \
              fa[i2][kx], fb[j2][kx], acc[(mq) * 2 + i2][(nq) * 2 + j2], 0, 0, 0); \
    __builtin_amdgcn_s_setprio(0); } while (0)

    f32x4 acc[4][4] = {};

    // prologue: stage tile 0 in unit order A, B0, B1 (6 vmem ops in flight)
    STAGE_A(As[0], 0);
    STAGE_B0(Bs[0], 0);
    STAGE_B1(Bs[0], 0);

    for (int kt = 0; kt < KTILES; ++kt) {
        const int cur = kt & 1;
        const int nxt = cur ^ 1;
        const int kn  = (kt + 1) & (KTILES - 1);   // wrap: tile-64 loads are harmless
        const u16* a = As[cur];
        const u16* b = Bs[cur];
        bf16x8 fA0[2][2], fA1[2][2], fB0[2][2], fB1[2][2];   // [i2][kx]

        // ---- ph0: quadrant (m0,n0). Needs A(t),B0(t); B1(t) still in flight.
        asm volatile("s_waitcnt vmcnt(2) lgkmcnt(0)" ::: "memory");
        __builtin_amdgcn_s_barrier();
        RD(fA0, a, wm);
        RD(fB0, b, wn);
        STAGE_A(As[nxt], kn);
        MM(fA0, fB0, 0, 0);

        // ---- ph1: quadrant (m0,n1). Needs B1(t); A(t+1) in flight.
        asm volatile("s_waitcnt vmcnt(2) lgkmcnt(0)" ::: "memory");
        __builtin_amdgcn_s_barrier();
        RD(fB1, b, wn + 32);
        STAGE_B0(Bs[nxt], kn);
        MM(fA0, fB1, 0, 1);

        // ---- ph2: quadrant (m1,n1). No new global data needed, no barrier.
        RD(fA1, a, wm + 32);
        STAGE_B1(Bs[nxt], kn);
        MM(fA1, fB1, 1, 1);

        // ---- ph3: quadrant (m1,n0). Pure reuse from registers.
        MM(fA1, fB0, 1, 0);
    }

    const int rb = q * 4;
#pragma unroll
    for (int i = 0; i < 4; ++i) {
#pragma unroll
        for (int j = 0; j < 4; ++j) {
            int n = bn * 256 + wn + j * 16 + fr;
            float bv = bias[n];
#pragma unroll
            for (int r = 0; r < 4; ++r) {
                int m = bm * 128 + wm + i * 16 + rb + r;
                C[(size_t)m * N_DIM + n] = acc[i][j][r] + bv;
            }
        }
    }
#undef STAGE_A
#undef STAGE_B0
#undef STAGE_B1
#undef RD
#undef MM
}

extern "C" void kernel_launch(void* const* d_in, const int* in_sizes, int n_in,
                              void* d_out, int out_size, void* d_ws, size_t ws_size,
                              hipStream_t stream) {
    const float* x    = (const float*)d_in[0];  // 2048 x 4096
    const float* mask = (const float*)d_in[1];  // 4096 x 4096
    const float* W    = (const float*)d_in[2];  // 4096 x 4096
    const float* bias = (const float*)d_in[3];  // 4096
    float* out = (float*)d_out;                 // 2048 x 4096

    u16* Bt = (u16*)d_ws;                                   // N*K bf16 = 32 MB
    u16* xb = (u16*)d_ws + (size_t)N_DIM * K_DIM;           // M*K bf16 = 16 MB

    // prep signature is (x, xb, W, Msk, Bt) — keep argument order exact.
    prep<<<4096, 256, 0, stream>>>(x, xb, W, mask, Bt);
    gemm8<<<dim3(N_DIM / 256, M_DIM / 128), 512, 0, stream>>>(xb, Bt, bias, out);
}

// Round 3
// 253.753 us; speedup vs baseline: 1.0459x; 1.0459x over previous
//
#include <hip/hip_runtime.h>

#define M_DIM 2048
#define K_DIM 4096
#define N_DIM 4096
#define KTILES (K_DIM / 64)

typedef unsigned short u16;
typedef unsigned int u32;
typedef __bf16 bf16x8 __attribute__((ext_vector_type(8)));
typedef float f32x4 __attribute__((ext_vector_type(4)));
typedef float f4 __attribute__((ext_vector_type(4)));
typedef u16 u16x8 __attribute__((ext_vector_type(8)));
typedef u32 u32x4 __attribute__((ext_vector_type(4)));

// fp32 -> bf16 round-to-nearest-even
__device__ __forceinline__ u16 f2bf(float f) {
    unsigned int u = __float_as_uint(f);
    u += 0x7fffu + ((u >> 16) & 1u);
    return (u16)(u >> 16);
}

// pack two fp32 -> (bf16(lo) | bf16(hi)<<16), RNE
__device__ __forceinline__ u32 pack2(float lo, float hi) {
    u32 a = __float_as_uint(lo); a += 0x7fffu + ((a >> 16) & 1u);
    u32 b = __float_as_uint(hi); b += 0x7fffu + ((b >> 16) & 1u);
    return (a >> 16) | (b & 0xffff0000u);
}

// async global->LDS, 16B per lane. LDS dest must be wave-uniform base + lane*16.
__device__ __forceinline__ void load16(const void* g, void* l) {
    __builtin_amdgcn_global_load_lds(
        (__attribute__((address_space(1))) const void*)g,
        (__attribute__((address_space(3))) void*)l,
        16, 0, 0);
}

// --------------- fused prep: LDS-free transpose + x->bf16 (UNCHANGED) -------
__global__ __launch_bounds__(256) void prep(const float* __restrict__ x,
                                            u16* __restrict__ xb,
                                            const float* __restrict__ W,
                                            const float* __restrict__ Msk,
                                            u16* __restrict__ Bt) {
    const int t = threadIdx.x;
    if (blockIdx.x >= 2048) {
        // ---- conv_x: 16 floats/thread ----
        size_t i = ((size_t)(blockIdx.x - 2048) * 256 + t) * 16;
#pragma unroll
        for (int h = 0; h < 2; ++h) {
            f4 v0 = *(const f4*)(x + i + h * 8);
            f4 v1 = *(const f4*)(x + i + h * 8 + 4);
            u16x8 o;
            o[0] = f2bf(v0[0]); o[1] = f2bf(v0[1]); o[2] = f2bf(v0[2]); o[3] = f2bf(v0[3]);
            o[4] = f2bf(v1[0]); o[5] = f2bf(v1[1]); o[6] = f2bf(v1[2]); o[7] = f2bf(v1[3]);
            *(u16x8*)(xb + i + h * 8) = o;
        }
        return;
    }
    const int n0 = (blockIdx.x & 31) * 128;         // 32 n-tiles of 128
    const int k0 = (blockIdx.x >> 5) * 64;          // 64 k-tiles of 64
    const int ko = t & 7;                           // k-octet within tile
    const int ng = t >> 3;                          // n-group (4 cols), 0..31

    const float* Wp = W   + (size_t)(k0 + 8 * ko) * N_DIM + n0 + 4 * ng;
    const float* Mp = Msk + (size_t)(k0 + 8 * ko) * N_DIM + n0 + 4 * ng;

    f4 a[8];
#pragma unroll
    for (int j = 0; j < 8; ++j) {
        f4 wv = *(const f4*)(Wp + (size_t)j * N_DIM);
        f4 mv = *(const f4*)(Mp + (size_t)j * N_DIM);
        a[j][0] = mv[0] != 0.f ? wv[0] : 0.f;
        a[j][1] = mv[1] != 0.f ? wv[1] : 0.f;
        a[j][2] = mv[2] != 0.f ? wv[2] : 0.f;
        a[j][3] = mv[3] != 0.f ? wv[3] : 0.f;
    }

    u16* bp = Bt + (size_t)(n0 + 4 * ng) * K_DIM + k0 + 8 * ko;
#pragma unroll
    for (int i = 0; i < 4; ++i) {                   // n within the float4
        u32x4 o;
        o[0] = pack2(a[0][i], a[1][i]);
        o[1] = pack2(a[2][i], a[3][i]);
        o[2] = pack2(a[4][i], a[5][i]);
        o[3] = pack2(a[6][i], a[7][i]);
        *(u32x4*)(bp + (size_t)i * K_DIM) = o;
    }
}

// ------- gemm8: 128m x 256n tile, template-faithful 2-phase + triple-buffer -
// 512 threads = 8 waves (2m x 4n), 64x64 output per wave. LDS TRIPLE-buffered
// (144 KB) so prefetch is 2 K-tiles deep: the per-tile wait is vmcnt(6)
// (tile t+1 certified, tile t+2's 6 loads stay in flight) and NEVER drains.
// Certification (vmcnt(6) + s_barrier) precedes every ds_read of a buffer:
// the R2 partial-tile race is closed by construction.
// Phase structure is the verified m201 template scaled down: per K-tile two
// phases, each {ds_read frags ∥ 3x global_load_lds stage -> s_barrier ->
// lgkmcnt(0) -> setprio(1) -> 16 MFMA -> setprio(0) -> s_barrier}.
// Swizzle / fragment layout / C-orientation identical to the verified kernel.
__global__ __launch_bounds__(512, 2) void gemm8(const u16* __restrict__ A,   // M x K bf16
                                                const u16* __restrict__ Bt,  // N x K bf16
                                                const float* __restrict__ bias,
                                                float* __restrict__ C) {
    __shared__ __align__(16) u16 As[3][128 * 64];   // 3 x 16 KB
    __shared__ __align__(16) u16 Bs[3][256 * 64];   // 3 x 32 KB

    const int t  = threadIdx.x;
    const int bn = blockIdx.x;      // N / 256
    const int bm = blockIdx.y;      // M / 128

    // staging: row = j*64 + (t>>3), phys chunk = t&7, pre-swizzled source
    // chunk = (t&7) ^ (row&7)  (row&7 == srow&7 since j*64 is a mult of 8)
    const int srow   = t >> 3;
    const int schunk = (t & 7) ^ (srow & 7);
    const u16* gA = A  + (size_t)(bm * 128 + srow) * K_DIM + schunk * 8;
    const u16* gB = Bt + (size_t)(bn * 256 + srow) * K_DIM + schunk * 8;

    const int lane = t & 63;
    const int wv   = t >> 6;
    const int wm = (wv >> 2) * 64;      // wave m-origin within A-tile (0/64)
    const int wn = (wv & 3) * 64;       // wave n-origin within B-tile (0..192)
    const int fr = lane & 15;
    const int q  = lane >> 4;
    const int sw = fr & 7;
    const int col0 = ((0 + q) ^ sw) * 8;    // kk = 0
    const int col1 = ((4 + q) ^ sw) * 8;    // kk = 32

    // single stage loads (per thread): A has 2 row-bands, B has 4
#define SA(buf, kt, j) load16(gA + (size_t)(kt) * 64 + (size_t)(j) * 64 * K_DIM, \
                              (buf) + (j) * 4096 + t * 8)
#define SB(buf, kt, j) load16(gB + (size_t)(kt) * 64 + (size_t)(j) * 64 * K_DIM, \
                              (buf) + (j) * 4096 + t * 8)

#define RD(dst, base, row0) do { \
    dst[0][0] = *(const bf16x8*)((base) + ((row0) + fr) * 64 + col0); \
    dst[0][1] = *(const bf16x8*)((base) + ((row0) + fr) * 64 + col1); \
    dst[1][0] = *(const bf16x8*)((base) + ((row0) + 16 + fr) * 64 + col0); \
    dst[1][1] = *(const bf16x8*)((base) + ((row0) + 16 + fr) * 64 + col1); } while (0)

#define MM(fa, fb, mq, nq) do { \
    _Pragma("unroll") \
    for (int kx = 0; kx < 2; ++kx) \
      _Pragma("unroll") \
      for (int i2 = 0; i2 < 2; ++i2) \
        _Pragma("unroll") \
        for (int j2 = 0; j2 < 2; ++j2) \
          acc[(mq) * 2 + i2][(nq) * 2 + j2] = __builtin_amdgcn_mfma_f32_16x16x32_bf16( \
              fa[i2][kx], fb[j2][kx], acc[(mq) * 2 + i2][(nq) * 2 + j2], 0, 0, 0); \
    } while (0)

    f32x4 acc[4][4] = {};

    // rotating buffer pointers (register-held; never runtime-indexed)
    u16 *aC = (u16*)As[0], *aN1 = (u16*)As[1], *aN2 = (u16*)As[2];
    u16 *bC = (u16*)Bs[0], *bN1 = (u16*)Bs[1], *bN2 = (u16*)Bs[2];

    // prologue: stage tiles 0 and 1 (12 loads in flight), certify tile 0
    SA(aC, 0, 0);  SA(aC, 0, 1);
    SB(bC, 0, 0);  SB(bC, 0, 1);  SB(bC, 0, 2);  SB(bC, 0, 3);
    SA(aN1, 1, 0); SA(aN1, 1, 1);
    SB(bN1, 1, 0); SB(bN1, 1, 1); SB(bN1, 1, 2); SB(bN1, 1, 3);
    asm volatile("s_waitcnt vmcnt(6)" ::: "memory");
    __builtin_amdgcn_s_barrier();

    for (int kt = 0; kt < KTILES; ++kt) {
        const int kn = (kt + 2) & (KTILES - 1);   // wrap loads: harmless re-stage
        bf16x8 fA0[2][2], fA1[2][2], fB0[2][2], fB1[2][2];

        // ---- ph0: quadrants (m0,n0)+(m0,n1); stage A(kn) + B-band0(kn) ----
        RD(fA0, aC, wm);
        RD(fB0, bC, wn);
        RD(fB1, bC, wn + 32);
        SA(aN2, kn, 0); SA(aN2, kn, 1); SB(bN2, kn, 0);
        __builtin_amdgcn_s_barrier();
        asm volatile("s_waitcnt lgkmcnt(0)" ::: "memory");
        __builtin_amdgcn_s_setprio(1);
        MM(fA0, fB0, 0, 0);
        MM(fA0, fB1, 0, 1);
        __builtin_amdgcn_s_setprio(0);
        __builtin_amdgcn_s_barrier();

        // ---- ph1: quadrants (m1,n1)+(m1,n0); stage B-bands 1..3(kn) -------
        RD(fA1, aC, wm + 32);
        SB(bN2, kn, 1); SB(bN2, kn, 2); SB(bN2, kn, 3);
        __builtin_amdgcn_s_barrier();
        asm volatile("s_waitcnt lgkmcnt(0)" ::: "memory");
        __builtin_amdgcn_s_setprio(1);
        MM(fA1, fB1, 1, 1);
        MM(fA1, fB0, 1, 0);
        __builtin_amdgcn_s_setprio(0);
        // certify tile kt+1 (its 6 loads are the oldest outstanding; tile
        // kt+2's 6 issued this iteration stay in flight) — never drains to 0
        asm volatile("s_waitcnt vmcnt(6)" ::: "memory");
        __builtin_amdgcn_s_barrier();

        // rotate buffers: tile T lives in buf[T % 3]
        u16* tmp;
        tmp = aC; aC = aN1; aN1 = aN2; aN2 = tmp;
        tmp = bC; bC = bN1; bN1 = bN2; bN2 = tmp;
    }

    const int rb = q * 4;
#pragma unroll
    for (int i = 0; i < 4; ++i) {
#pragma unroll
        for (int j = 0; j < 4; ++j) {
            int n = bn * 256 + wn + j * 16 + fr;
            float bv = bias[n];
#pragma unroll
            for (int r = 0; r < 4; ++r) {
                int m = bm * 128 + wm + i * 16 + rb + r;
                C[(size_t)m * N_DIM + n] = acc[i][j][r] + bv;
            }
        }
    }
#undef SA
#undef SB
#undef RD
#undef MM
}

extern "C" void kernel_launch(void* const* d_in, const int* in_sizes, int n_in,
                              void* d_out, int out_size, void* d_ws, size_t ws_size,
                              hipStream_t stream) {
    const float* x    = (const float*)d_in[0];  // 2048 x 4096
    const float* mask = (const float*)d_in[1];  // 4096 x 4096
    const float* W    = (const float*)d_in[2];  // 4096 x 4096
    const float* bias = (const float*)d_in[3];  // 4096
    float* out = (float*)d_out;                 // 2048 x 4096

    u16* Bt = (u16*)d_ws;                                   // N*K bf16 = 32 MB
    u16* xb = (u16*)d_ws + (size_t)N_DIM * K_DIM;           // M*K bf16 = 16 MB

    // prep signature is (x, xb, W, Msk, Bt) — keep argument order exact.
    prep<<<4096, 256, 0, stream>>>(x, xb, W, mask, Bt);
    gemm8<<<dim3(N_DIM / 256, M_DIM / 128), 512, 0, stream>>>(xb, Bt, bias, out);
}

// Round 4
// 250.908 us; speedup vs baseline: 1.0578x; 1.0113x over previous
//
#include <hip/hip_runtime.h>

#define M_DIM 2048
#define K_DIM 4096
#define N_DIM 4096
#define KTILES (K_DIM / 64)

typedef unsigned short u16;
typedef unsigned int u32;
typedef __bf16 bf16x8 __attribute__((ext_vector_type(8)));
typedef float f32x4 __attribute__((ext_vector_type(4)));
typedef float f4 __attribute__((ext_vector_type(4)));
typedef u16 u16x8 __attribute__((ext_vector_type(8)));
typedef u32 u32x4 __attribute__((ext_vector_type(4)));

// fp32 -> bf16 round-to-nearest-even
__device__ __forceinline__ u16 f2bf(float f) {
    unsigned int u = __float_as_uint(f);
    u += 0x7fffu + ((u >> 16) & 1u);
    return (u16)(u >> 16);
}

// pack two fp32 -> (bf16(lo) | bf16(hi)<<16), RNE
__device__ __forceinline__ u32 pack2(float lo, float hi) {
    u32 a = __float_as_uint(lo); a += 0x7fffu + ((a >> 16) & 1u);
    u32 b = __float_as_uint(hi); b += 0x7fffu + ((b >> 16) & 1u);
    return (a >> 16) | (b & 0xffff0000u);
}

// async global->LDS, 16B per lane. LDS dest must be wave-uniform base + lane*16.
__device__ __forceinline__ void load16(const void* g, void* l) {
    __builtin_amdgcn_global_load_lds(
        (__attribute__((address_space(1))) const void*)g,
        (__attribute__((address_space(3))) void*)l,
        16, 0, 0);
}

// ------- prep_t: LDS-free transpose, Bt[n][k] = bf16((mask?W:0)[k][n]) ------
// One 64(k) x 128(n) tile per block. Thread t owns k-octet ko = t&7 and 4
// n-columns (ng = t>>3): 8x float4 from W and Msk (per-wave 128B-contiguous
// segments), mask+pack in registers (pack2 pairs k,k+1 -> transpose is
// intra-thread), store one uint4 per n (128B-contiguous per octet-group).
// SPLIT OUT from the fused prep so its timing shows in the counter table.
__global__ __launch_bounds__(256) void prep_t(const float* __restrict__ W,
                                              const float* __restrict__ Msk,
                                              u16* __restrict__ Bt) {
    const int t = threadIdx.x;
    const int n0 = (blockIdx.x & 31) * 128;         // 32 n-tiles of 128
    const int k0 = (blockIdx.x >> 5) * 64;          // 64 k-tiles of 64
    const int ko = t & 7;                           // k-octet within tile
    const int ng = t >> 3;                          // n-group (4 cols), 0..31

    const float* Wp = W   + (size_t)(k0 + 8 * ko) * N_DIM + n0 + 4 * ng;
    const float* Mp = Msk + (size_t)(k0 + 8 * ko) * N_DIM + n0 + 4 * ng;

    f4 a[8];
#pragma unroll
    for (int j = 0; j < 8; ++j) {
        f4 wv = *(const f4*)(Wp + (size_t)j * N_DIM);
        f4 mv = *(const f4*)(Mp + (size_t)j * N_DIM);
        a[j][0] = mv[0] != 0.f ? wv[0] : 0.f;
        a[j][1] = mv[1] != 0.f ? wv[1] : 0.f;
        a[j][2] = mv[2] != 0.f ? wv[2] : 0.f;
        a[j][3] = mv[3] != 0.f ? wv[3] : 0.f;
    }

    u16* bp = Bt + (size_t)(n0 + 4 * ng) * K_DIM + k0 + 8 * ko;
#pragma unroll
    for (int i = 0; i < 4; ++i) {                   // n within the float4
        u32x4 o;
        o[0] = pack2(a[0][i], a[1][i]);
        o[1] = pack2(a[2][i], a[3][i]);
        o[2] = pack2(a[4][i], a[5][i]);
        o[3] = pack2(a[6][i], a[7][i]);
        *(u32x4*)(bp + (size_t)i * K_DIM) = o;
    }
}

// ------------------- prep_x: x f32 -> bf16, 16 floats/thread ----------------
__global__ __launch_bounds__(256) void prep_x(const float* __restrict__ x,
                                              u16* __restrict__ xb) {
    const int t = threadIdx.x;
    size_t i = ((size_t)blockIdx.x * 256 + t) * 16;
#pragma unroll
    for (int h = 0; h < 2; ++h) {
        f4 v0 = *(const f4*)(x + i + h * 8);
        f4 v1 = *(const f4*)(x + i + h * 8 + 4);
        u16x8 o;
        o[0] = f2bf(v0[0]); o[1] = f2bf(v0[1]); o[2] = f2bf(v0[2]); o[3] = f2bf(v0[3]);
        o[4] = f2bf(v1[0]); o[5] = f2bf(v1[1]); o[6] = f2bf(v1[2]); o[7] = f2bf(v1[3]);
        *(u16x8*)(xb + i + h * 8) = o;
    }
}

// ------- gemm8: 128m x 256n tile, 2-phase + triple-buffer (UNCHANGED R3) ----
// 512 threads = 8 waves (2m x 4n), 64x64 output per wave. LDS triple-buffered
// (144 KB), prefetch 2 K-tiles deep, per-tile wait vmcnt(6) never drains.
// Verified 77.2 us / 893 TF / MfmaUtil 36 / conflicts 0.
__global__ __launch_bounds__(512, 2) void gemm8(const u16* __restrict__ A,   // M x K bf16
                                                const u16* __restrict__ Bt,  // N x K bf16
                                                const float* __restrict__ bias,
                                                float* __restrict__ C) {
    __shared__ __align__(16) u16 As[3][128 * 64];   // 3 x 16 KB
    __shared__ __align__(16) u16 Bs[3][256 * 64];   // 3 x 32 KB

    const int t  = threadIdx.x;
    const int bn = blockIdx.x;      // N / 256
    const int bm = blockIdx.y;      // M / 128

    const int srow   = t >> 3;
    const int schunk = (t & 7) ^ (srow & 7);
    const u16* gA = A  + (size_t)(bm * 128 + srow) * K_DIM + schunk * 8;
    const u16* gB = Bt + (size_t)(bn * 256 + srow) * K_DIM + schunk * 8;

    const int lane = t & 63;
    const int wv   = t >> 6;
    const int wm = (wv >> 2) * 64;      // wave m-origin within A-tile (0/64)
    const int wn = (wv & 3) * 64;       // wave n-origin within B-tile (0..192)
    const int fr = lane & 15;
    const int q  = lane >> 4;
    const int sw = fr & 7;
    const int col0 = ((0 + q) ^ sw) * 8;    // kk = 0
    const int col1 = ((4 + q) ^ sw) * 8;    // kk = 32

#define SA(buf, kt, j) load16(gA + (size_t)(kt) * 64 + (size_t)(j) * 64 * K_DIM, \
                              (buf) + (j) * 4096 + t * 8)
#define SB(buf, kt, j) load16(gB + (size_t)(kt) * 64 + (size_t)(j) * 64 * K_DIM, \
                              (buf) + (j) * 4096 + t * 8)

#define RD(dst, base, row0) do { \
    dst[0][0] = *(const bf16x8*)((base) + ((row0) + fr) * 64 + col0); \
    dst[0][1] = *(const bf16x8*)((base) + ((row0) + fr) * 64 + col1); \
    dst[1][0] = *(const bf16x8*)((base) + ((row0) + 16 + fr) * 64 + col0); \
    dst[1][1] = *(const bf16x8*)((base) + ((row0) + 16 + fr) * 64 + col1); } while (0)

#define MM(fa, fb, mq, nq) do { \
    _Pragma("unroll") \
    for (int kx = 0; kx < 2; ++kx) \
      _Pragma("unroll") \
      for (int i2 = 0; i2 < 2; ++i2) \
        _Pragma("unroll") \
        for (int j2 = 0; j2 < 2; ++j2) \
          acc[(mq) * 2 + i2][(nq) * 2 + j2] = __builtin_amdgcn_mfma_f32_16x16x32_bf16( \
              fa[i2][kx], fb[j2][kx], acc[(mq) * 2 + i2][(nq) * 2 + j2], 0, 0, 0); \
    } while (0)

    f32x4 acc[4][4] = {};

    // rotating buffer pointers (register-held; never runtime-indexed)
    u16 *aC = (u16*)As[0], *aN1 = (u16*)As[1], *aN2 = (u16*)As[2];
    u16 *bC = (u16*)Bs[0], *bN1 = (u16*)Bs[1], *bN2 = (u16*)Bs[2];

    // prologue: stage tiles 0 and 1 (12 loads in flight), certify tile 0
    SA(aC, 0, 0);  SA(aC, 0, 1);
    SB(bC, 0, 0);  SB(bC, 0, 1);  SB(bC, 0, 2);  SB(bC, 0, 3);
    SA(aN1, 1, 0); SA(aN1, 1, 1);
    SB(bN1, 1, 0); SB(bN1, 1, 1); SB(bN1, 1, 2); SB(bN1, 1, 3);
    asm volatile("s_waitcnt vmcnt(6)" ::: "memory");
    __builtin_amdgcn_s_barrier();

    for (int kt = 0; kt < KTILES; ++kt) {
        const int kn = (kt + 2) & (KTILES - 1);   // wrap loads: harmless re-stage
        bf16x8 fA0[2][2], fA1[2][2], fB0[2][2], fB1[2][2];

        // ---- ph0: quadrants (m0,n0)+(m0,n1); stage A(kn) + B-band0(kn) ----
        RD(fA0, aC, wm);
        RD(fB0, bC, wn);
        RD(fB1, bC, wn + 32);
        SA(aN2, kn, 0); SA(aN2, kn, 1); SB(bN2, kn, 0);
        __builtin_amdgcn_s_barrier();
        asm volatile("s_waitcnt lgkmcnt(0)" ::: "memory");
        __builtin_amdgcn_s_setprio(1);
        MM(fA0, fB0, 0, 0);
        MM(fA0, fB1, 0, 1);
        __builtin_amdgcn_s_setprio(0);
        __builtin_amdgcn_s_barrier();

        // ---- ph1: quadrants (m1,n1)+(m1,n0); stage B-bands 1..3(kn) -------
        RD(fA1, aC, wm + 32);
        SB(bN2, kn, 1); SB(bN2, kn, 2); SB(bN2, kn, 3);
        __builtin_amdgcn_s_barrier();
        asm volatile("s_waitcnt lgkmcnt(0)" ::: "memory");
        __builtin_amdgcn_s_setprio(1);
        MM(fA1, fB1, 1, 1);
        MM(fA1, fB0, 1, 0);
        __builtin_amdgcn_s_setprio(0);
        // certify tile kt+1 (its 6 loads are the oldest outstanding) —
        // tile kt+2's 6 loads stay in flight; never drains to 0
        asm volatile("s_waitcnt vmcnt(6)" ::: "memory");
        __builtin_amdgcn_s_barrier();

        // rotate buffers: tile T lives in buf[T % 3]
        u16* tmp;
        tmp = aC; aC = aN1; aN1 = aN2; aN2 = tmp;
        tmp = bC; bC = bN1; bN1 = bN2; bN2 = tmp;
    }

    const int rb = q * 4;
#pragma unroll
    for (int i = 0; i < 4; ++i) {
#pragma unroll
        for (int j = 0; j < 4; ++j) {
            int n = bn * 256 + wn + j * 16 + fr;
            float bv = bias[n];
#pragma unroll
            for (int r = 0; r < 4; ++r) {
                int m = bm * 128 + wm + i * 16 + rb + r;
                C[(size_t)m * N_DIM + n] = acc[i][j][r] + bv;
            }
        }
    }
#undef SA
#undef SB
#undef RD
#undef MM
}

extern "C" void kernel_launch(void* const* d_in, const int* in_sizes, int n_in,
                              void* d_out, int out_size, void* d_ws, size_t ws_size,
                              hipStream_t stream) {
    const float* x    = (const float*)d_in[0];  // 2048 x 4096
    const float* mask = (const float*)d_in[1];  // 4096 x 4096
    const float* W    = (const float*)d_in[2];  // 4096 x 4096
    const float* bias = (const float*)d_in[3];  // 4096
    float* out = (float*)d_out;                 // 2048 x 4096

    u16* Bt = (u16*)d_ws;                                   // N*K bf16 = 32 MB
    u16* xb = (u16*)d_ws + (size_t)N_DIM * K_DIM;           // M*K bf16 = 16 MB

    prep_t<<<2048, 256, 0, stream>>>(W, mask, Bt);
    prep_x<<<2048, 256, 0, stream>>>(x, xb);
    gemm8<<<dim3(N_DIM / 256, M_DIM / 128), 512, 0, stream>>>(xb, Bt, bias, out);
}

// Round 5
// 249.146 us; speedup vs baseline: 1.0652x; 1.0071x over previous
//
#include <hip/hip_runtime.h>

#define M_DIM 2048
#define K_DIM 4096
#define N_DIM 4096
#define KTILES (K_DIM / 64)

typedef unsigned short u16;
typedef unsigned int u32;
typedef __bf16 bf16x8 __attribute__((ext_vector_type(8)));
typedef float f32x4 __attribute__((ext_vector_type(4)));
typedef float f4 __attribute__((ext_vector_type(4)));
typedef u16 u16x8 __attribute__((ext_vector_type(8)));
typedef u32 u32x4 __attribute__((ext_vector_type(4)));

// fp32 -> bf16 round-to-nearest-even
__device__ __forceinline__ u16 f2bf(float f) {
    unsigned int u = __float_as_uint(f);
    u += 0x7fffu + ((u >> 16) & 1u);
    return (u16)(u >> 16);
}

// pack two fp32 -> (bf16(lo) | bf16(hi)<<16), RNE
__device__ __forceinline__ u32 pack2(float lo, float hi) {
    u32 a = __float_as_uint(lo); a += 0x7fffu + ((a >> 16) & 1u);
    u32 b = __float_as_uint(hi); b += 0x7fffu + ((b >> 16) & 1u);
    return (a >> 16) | (b & 0xffff0000u);
}

// async global->LDS, 16B per lane. LDS dest must be wave-uniform base + lane*16.
__device__ __forceinline__ void load16(const void* g, void* l) {
    __builtin_amdgcn_global_load_lds(
        (__attribute__((address_space(1))) const void*)g,
        (__attribute__((address_space(3))) void*)l,
        16, 0, 0);
}

// ------- prep_t: LDS-free transpose, Bt[n][k] = bf16((mask?W:0)[k][n]) ------
__global__ __launch_bounds__(256) void prep_t(const float* __restrict__ W,
                                              const float* __restrict__ Msk,
                                              u16* __restrict__ Bt) {
    const int t = threadIdx.x;
    const int n0 = (blockIdx.x & 31) * 128;         // 32 n-tiles of 128
    const int k0 = (blockIdx.x >> 5) * 64;          // 64 k-tiles of 64
    const int ko = t & 7;                           // k-octet within tile
    const int ng = t >> 3;                          // n-group (4 cols), 0..31

    const float* Wp = W   + (size_t)(k0 + 8 * ko) * N_DIM + n0 + 4 * ng;
    const float* Mp = Msk + (size_t)(k0 + 8 * ko) * N_DIM + n0 + 4 * ng;

    f4 a[8];
#pragma unroll
    for (int j = 0; j < 8; ++j) {
        f4 wv = *(const f4*)(Wp + (size_t)j * N_DIM);
        f4 mv = *(const f4*)(Mp + (size_t)j * N_DIM);
        a[j][0] = mv[0] != 0.f ? wv[0] : 0.f;
        a[j][1] = mv[1] != 0.f ? wv[1] : 0.f;
        a[j][2] = mv[2] != 0.f ? wv[2] : 0.f;
        a[j][3] = mv[3] != 0.f ? wv[3] : 0.f;
    }

    u16* bp = Bt + (size_t)(n0 + 4 * ng) * K_DIM + k0 + 8 * ko;
#pragma unroll
    for (int i = 0; i < 4; ++i) {                   // n within the float4
        u32x4 o;
        o[0] = pack2(a[0][i], a[1][i]);
        o[1] = pack2(a[2][i], a[3][i]);
        o[2] = pack2(a[4][i], a[5][i]);
        o[3] = pack2(a[6][i], a[7][i]);
        *(u32x4*)(bp + (size_t)i * K_DIM) = o;
    }
}

// ------------------- prep_x: x f32 -> bf16, 16 floats/thread ----------------
__global__ __launch_bounds__(256) void prep_x(const float* __restrict__ x,
                                              u16* __restrict__ xb) {
    const int t = threadIdx.x;
    size_t i = ((size_t)blockIdx.x * 256 + t) * 16;
#pragma unroll
    for (int h = 0; h < 2; ++h) {
        f4 v0 = *(const f4*)(x + i + h * 8);
        f4 v1 = *(const f4*)(x + i + h * 8 + 4);
        u16x8 o;
        o[0] = f2bf(v0[0]); o[1] = f2bf(v0[1]); o[2] = f2bf(v0[2]); o[3] = f2bf(v0[3]);
        o[4] = f2bf(v1[0]); o[5] = f2bf(v1[1]); o[6] = f2bf(v1[2]); o[7] = f2bf(v1[3]);
        *(u16x8*)(xb + i + h * 8) = o;
    }
}

// --- gemm8: 128m x 256n tile, waves = 2m x 2n x 2k, 64m x 128n per wave -----
// Same R3-verified skeleton (triple-buffer, 2 phases/K-tile, vmcnt(6) never
// drains in the loop), but waves are split over K: wave kh = wv>>2 consumes
// k-halves [kh*32, kh*32+32) of every K-tile, with a 64m x 128n output tile.
// LDS arithmetic intensity rises 32 -> 43.7 FLOP/byte (12 ds_read_b128 per
// wave per K-tile for the same 32 MFMA): per-CU LDS reads drop 128->96 KB per
// K-tile, which was the binding pipe (3 schedules all plateaued at 36% Mfma).
// Epilogue: kh=1 waves dump acc to the (vmcnt(0)-drained) LDS buffers; kh=0
// waves add, apply bias, and write C. Swizzle algebra and C orientation are
// identical to the verified kernel (kh merely selects col0 vs col1).
__global__ __launch_bounds__(512, 2) void gemm8(const u16* __restrict__ A,   // M x K bf16
                                                const u16* __restrict__ Bt,  // N x K bf16
                                                const float* __restrict__ bias,
                                                float* __restrict__ C) {
    __shared__ __align__(16) u16 As[3][128 * 64];   // 3 x 16 KB
    __shared__ __align__(16) u16 Bs[3][256 * 64];   // 3 x 32 KB

    const int t  = threadIdx.x;
    const int bn = blockIdx.x;      // N / 256
    const int bm = blockIdx.y;      // M / 128

    const int srow   = t >> 3;
    const int schunk = (t & 7) ^ (srow & 7);
    const u16* gA = A  + (size_t)(bm * 128 + srow) * K_DIM + schunk * 8;
    const u16* gB = Bt + (size_t)(bn * 256 + srow) * K_DIM + schunk * 8;

    const int lane = t & 63;
    const int wv   = t >> 6;
    const int kh = wv >> 2;             // k-half of every K-tile (0/1)
    const int wq = wv & 3;              // position in 2m x 2n wave grid
    const int mo = (wq >> 1) * 64;      // wave m-origin (0/64)
    const int no = (wq & 1) * 128;      // wave n-origin (0/128)
    const int fr = lane & 15;
    const int q  = lane >> 4;
    const int sw = fr & 7;
    // logical k-chunk = kh*4 + q; physical col via the staging XOR swizzle
    const int colK = (((kh << 2) + q) ^ sw) * 8;

#define SA(buf, kt, j) load16(gA + (size_t)(kt) * 64 + (size_t)(j) * 64 * K_DIM, \
                              (buf) + (j) * 4096 + t * 8)
#define SB(buf, kt, j) load16(gB + (size_t)(kt) * 64 + (size_t)(j) * 64 * K_DIM, \
                              (buf) + (j) * 4096 + t * 8)

    f32x4 acc[4][8] = {};   // [i: m 4x16][j: n 8x16]

    // rotating buffer pointers (register-held; never runtime-indexed)
    u16 *aC = (u16*)As[0], *aN1 = (u16*)As[1], *aN2 = (u16*)As[2];
    u16 *bC = (u16*)Bs[0], *bN1 = (u16*)Bs[1], *bN2 = (u16*)Bs[2];

    // prologue: stage tiles 0 and 1 (12 loads in flight), certify tile 0
    SA(aC, 0, 0);  SA(aC, 0, 1);
    SB(bC, 0, 0);  SB(bC, 0, 1);  SB(bC, 0, 2);  SB(bC, 0, 3);
    SA(aN1, 1, 0); SA(aN1, 1, 1);
    SB(bN1, 1, 0); SB(bN1, 1, 1); SB(bN1, 1, 2); SB(bN1, 1, 3);
    asm volatile("s_waitcnt vmcnt(6)" ::: "memory");
    __builtin_amdgcn_s_barrier();

    for (int kt = 0; kt < KTILES; ++kt) {
        const int kn = (kt + 2) & (KTILES - 1);   // wrap loads: harmless re-stage
        bf16x8 fA[4], fB0[4], fB1[4];

        // ---- ph0: n-half 0 (j=0..3); stage A(kn) + B-band0(kn) ------------
#pragma unroll
        for (int i = 0; i < 4; ++i)
            fA[i] = *(const bf16x8*)(aC + (mo + i * 16 + fr) * 64 + colK);
#pragma unroll
        for (int j = 0; j < 4; ++j)
            fB0[j] = *(const bf16x8*)(bC + (no + j * 16 + fr) * 64 + colK);
        SA(aN2, kn, 0); SA(aN2, kn, 1); SB(bN2, kn, 0);
        __builtin_amdgcn_s_barrier();
        asm volatile("s_waitcnt lgkmcnt(0)" ::: "memory");
        __builtin_amdgcn_s_setprio(1);
#pragma unroll
        for (int i = 0; i < 4; ++i)
#pragma unroll
            for (int j = 0; j < 4; ++j)
                acc[i][j] = __builtin_amdgcn_mfma_f32_16x16x32_bf16(
                    fA[i], fB0[j], acc[i][j], 0, 0, 0);
        __builtin_amdgcn_s_setprio(0);
        __builtin_amdgcn_s_barrier();

        // ---- ph1: n-half 1 (j=4..7); stage B-bands 1..3(kn) ---------------
#pragma unroll
        for (int j = 0; j < 4; ++j)
            fB1[j] = *(const bf16x8*)(bC + (no + 64 + j * 16 + fr) * 64 + colK);
        SB(bN2, kn, 1); SB(bN2, kn, 2); SB(bN2, kn, 3);
        __builtin_amdgcn_s_barrier();
        asm volatile("s_waitcnt lgkmcnt(0)" ::: "memory");
        __builtin_amdgcn_s_setprio(1);
#pragma unroll
        for (int i = 0; i < 4; ++i)
#pragma unroll
            for (int j = 0; j < 4; ++j)
                acc[i][j + 4] = __builtin_amdgcn_mfma_f32_16x16x32_bf16(
                    fA[i], fB1[j], acc[i][j + 4], 0, 0, 0);
        __builtin_amdgcn_s_setprio(0);
        // certify tile kt+1 (oldest 6 outstanding); kt+2's 6 stay in flight
        asm volatile("s_waitcnt vmcnt(6)" ::: "memory");
        __builtin_amdgcn_s_barrier();

        // rotate buffers: tile T lives in buf[T % 3]
        u16* tmp;
        tmp = aC; aC = aN1; aN1 = aN2; aN2 = tmp;
        tmp = bC; bC = bN1; bN1 = bN2; bN2 = tmp;
    }

    // ---- epilogue: cross-k-half reduction through LDS ----------------------
    // Drain all wrap-around global_load_lds before reusing the buffers.
    asm volatile("s_waitcnt vmcnt(0)" ::: "memory");
    __builtin_amdgcn_s_barrier();

    // 32 KB region per wq: wq 0..2 -> Bs[wq] (32 KB each), wq 3 -> As (48 KB)
    float* red = (wq == 3) ? (float*)As : (float*)Bs[wq];

    if (kh == 1) {
#pragma unroll
        for (int i = 0; i < 4; ++i)
#pragma unroll
            for (int j = 0; j < 8; ++j)
                *(f32x4*)(red + (i * 8 + j) * 256 + lane * 4) = acc[i][j];
    }
    asm volatile("s_waitcnt lgkmcnt(0)" ::: "memory");
    __builtin_amdgcn_s_barrier();

    if (kh == 0) {
        const int rb = q * 4;
#pragma unroll
        for (int i = 0; i < 4; ++i) {
#pragma unroll
            for (int j = 0; j < 8; ++j) {
                f32x4 other = *(const f32x4*)(red + (i * 8 + j) * 256 + lane * 4);
                int n = bn * 256 + no + j * 16 + fr;
                float bv = bias[n];
#pragma unroll
                for (int r = 0; r < 4; ++r) {
                    int m = bm * 128 + mo + i * 16 + rb + r;
                    C[(size_t)m * N_DIM + n] = acc[i][j][r] + other[r] + bv;
                }
            }
        }
    }
#undef SA
#undef SB
}

extern "C" void kernel_launch(void* const* d_in, const int* in_sizes, int n_in,
                              void* d_out, int out_size, void* d_ws, size_t ws_size,
                              hipStream_t stream) {
    const float* x    = (const float*)d_in[0];  // 2048 x 4096
    const float* mask = (const float*)d_in[1];  // 4096 x 4096
    const float* W    = (const float*)d_in[2];  // 4096 x 4096
    const float* bias = (const float*)d_in[3];  // 4096
    float* out = (float*)d_out;                 // 2048 x 4096

    u16* Bt = (u16*)d_ws;                                   // N*K bf16 = 32 MB
    u16* xb = (u16*)d_ws + (size_t)N_DIM * K_DIM;           // M*K bf16 = 16 MB

    prep_t<<<2048, 256, 0, stream>>>(W, mask, Bt);
    prep_x<<<2048, 256, 0, stream>>>(x, xb);
    gemm8<<<dim3(N_DIM / 256, M_DIM / 128), 512, 0, stream>>>(xb, Bt, bias, out);
}

// Round 6
// 244.561 us; speedup vs baseline: 1.0852x; 1.0187x over previous
//
#include <hip/hip_runtime.h>

#define M_DIM 2048
#define K_DIM 4096
#define N_DIM 4096
#define KTILES (K_DIM / 64)

typedef unsigned short u16;
typedef unsigned int u32;
typedef __bf16 bf16x8 __attribute__((ext_vector_type(8)));
typedef float f32x4 __attribute__((ext_vector_type(4)));
typedef float f4 __attribute__((ext_vector_type(4)));
typedef u16 u16x8 __attribute__((ext_vector_type(8)));
typedef u32 u32x4 __attribute__((ext_vector_type(4)));

// fp32 -> bf16 round-to-nearest-even
__device__ __forceinline__ u16 f2bf(float f) {
    unsigned int u = __float_as_uint(f);
    u += 0x7fffu + ((u >> 16) & 1u);
    return (u16)(u >> 16);
}

// pack two fp32 -> (bf16(lo) | bf16(hi)<<16), RNE
__device__ __forceinline__ u32 pack2(float lo, float hi) {
    u32 a = __float_as_uint(lo); a += 0x7fffu + ((a >> 16) & 1u);
    u32 b = __float_as_uint(hi); b += 0x7fffu + ((b >> 16) & 1u);
    return (a >> 16) | (b & 0xffff0000u);
}

// async global->LDS, 16B per lane. LDS dest must be wave-uniform base + lane*16.
__device__ __forceinline__ void load16(const void* g, void* l) {
    __builtin_amdgcn_global_load_lds(
        (__attribute__((address_space(1))) const void*)g,
        (__attribute__((address_space(3))) void*)l,
        16, 0, 0);
}

// ------- prep_t: LDS-free transpose, Bt[n][k] = bf16((mask?W:0)[k][n]) ------
__global__ __launch_bounds__(256) void prep_t(const float* __restrict__ W,
                                              const float* __restrict__ Msk,
                                              u16* __restrict__ Bt) {
    const int t = threadIdx.x;
    const int n0 = (blockIdx.x & 31) * 128;         // 32 n-tiles of 128
    const int k0 = (blockIdx.x >> 5) * 64;          // 64 k-tiles of 64
    const int ko = t & 7;                           // k-octet within tile
    const int ng = t >> 3;                          // n-group (4 cols), 0..31

    const float* Wp = W   + (size_t)(k0 + 8 * ko) * N_DIM + n0 + 4 * ng;
    const float* Mp = Msk + (size_t)(k0 + 8 * ko) * N_DIM + n0 + 4 * ng;

    f4 a[8];
#pragma unroll
    for (int j = 0; j < 8; ++j) {
        f4 wv = *(const f4*)(Wp + (size_t)j * N_DIM);
        f4 mv = *(const f4*)(Mp + (size_t)j * N_DIM);
        a[j][0] = mv[0] != 0.f ? wv[0] : 0.f;
        a[j][1] = mv[1] != 0.f ? wv[1] : 0.f;
        a[j][2] = mv[2] != 0.f ? wv[2] : 0.f;
        a[j][3] = mv[3] != 0.f ? wv[3] : 0.f;
    }

    u16* bp = Bt + (size_t)(n0 + 4 * ng) * K_DIM + k0 + 8 * ko;
#pragma unroll
    for (int i = 0; i < 4; ++i) {                   // n within the float4
        u32x4 o;
        o[0] = pack2(a[0][i], a[1][i]);
        o[1] = pack2(a[2][i], a[3][i]);
        o[2] = pack2(a[4][i], a[5][i]);
        o[3] = pack2(a[6][i], a[7][i]);
        *(u32x4*)(bp + (size_t)i * K_DIM) = o;
    }
}

// ------------------- prep_x: x f32 -> bf16, 16 floats/thread ----------------
__global__ __launch_bounds__(256) void prep_x(const float* __restrict__ x,
                                              u16* __restrict__ xb) {
    const int t = threadIdx.x;
    size_t i = ((size_t)blockIdx.x * 256 + t) * 16;
#pragma unroll
    for (int h = 0; h < 2; ++h) {
        f4 v0 = *(const f4*)(x + i + h * 8);
        f4 v1 = *(const f4*)(x + i + h * 8 + 4);
        u16x8 o;
        o[0] = f2bf(v0[0]); o[1] = f2bf(v0[1]); o[2] = f2bf(v0[2]); o[3] = f2bf(v0[3]);
        o[4] = f2bf(v1[0]); o[5] = f2bf(v1[1]); o[6] = f2bf(v1[2]); o[7] = f2bf(v1[3]);
        *(u16x8*)(xb + i + h * 8) = o;
    }
}

// --- gemm8: 128m x 256n tile, 2m x 2n x 2k waves, 1-barrier covered-wait loop
// R5 dataflow (triple-buffer, k-split waves, LDS cross-k reduce epilogue) with
// a restructured sync skeleton: per K-tile ONE s_barrier and ZERO naked waits.
//   [12 ds_read frags][stage A+B0][lgkmcnt(4): certifies the 8 A/B0 reads,
//    covered by issue work][16 MFMA][lgkmcnt(0): certifies B1, covered by the
//    MFMA cluster][stage B1..3][16 MFMA][vmcnt(6): certifies tile kt+1, ~1
//    iteration of cover][s_barrier]
// Hazards: nobody writes buf kt%3 during iter kt; writes to (kt+2)%3 start
// only after its readers (tile kt-1) were lgkm-certified before the previous
// barrier. sched_barrier(0) after each wait stops MFMA hoisting (rule #18).
// T1: bijective XCD swizzle (1D grid 256, 8bm x 4bn chunk per XCD).
__global__ __launch_bounds__(512, 2) void gemm8(const u16* __restrict__ A,   // M x K bf16
                                                const u16* __restrict__ Bt,  // N x K bf16
                                                const float* __restrict__ bias,
                                                float* __restrict__ C) {
    __shared__ __align__(16) u16 As[3][128 * 64];   // 3 x 16 KB
    __shared__ __align__(16) u16 Bs[3][256 * 64];   // 3 x 32 KB

    const int t = threadIdx.x;
    // XCD-aware decode: XCD x owns an 8(bm) x 4(bn) chunk -> 16 MB working set
    const int wgid = blockIdx.x;        // 256 WGs, wgid%8 == XCD [m09]
    const int xcd = wgid & 7, c = wgid >> 3;
    const int bm = (xcd & 1) * 8 + (c & 7);     // M/128 = 16
    const int bn = (xcd >> 1) * 4 + (c >> 3);   // N/256 = 16

    const int srow   = t >> 3;
    const int schunk = (t & 7) ^ (srow & 7);
    const u16* gA = A  + (size_t)(bm * 128 + srow) * K_DIM + schunk * 8;
    const u16* gB = Bt + (size_t)(bn * 256 + srow) * K_DIM + schunk * 8;

    const int lane = t & 63;
    const int wv   = t >> 6;
    const int kh = wv >> 2;             // k-half of every K-tile (0/1)
    const int wq = wv & 3;              // position in 2m x 2n wave grid
    const int mo = (wq >> 1) * 64;      // wave m-origin (0/64)
    const int no = (wq & 1) * 128;      // wave n-origin (0/128)
    const int fr = lane & 15;
    const int q  = lane >> 4;
    const int sw = fr & 7;
    const int colK = (((kh << 2) + q) ^ sw) * 8;

#define SA(buf, kt, j) load16(gA + (size_t)(kt) * 64 + (size_t)(j) * 64 * K_DIM, \
                              (buf) + (j) * 4096 + t * 8)
#define SB(buf, kt, j) load16(gB + (size_t)(kt) * 64 + (size_t)(j) * 64 * K_DIM, \
                              (buf) + (j) * 4096 + t * 8)

    f32x4 acc[4][8] = {};   // [i: m 4x16][j: n 8x16]

    // rotating buffer pointers (register-held; never runtime-indexed)
    u16 *aC = (u16*)As[0], *aN1 = (u16*)As[1], *aN2 = (u16*)As[2];
    u16 *bC = (u16*)Bs[0], *bN1 = (u16*)Bs[1], *bN2 = (u16*)Bs[2];

    // prologue: stage tiles 0 and 1 (12 loads in flight), certify tile 0
    SA(aC, 0, 0);  SA(aC, 0, 1);
    SB(bC, 0, 0);  SB(bC, 0, 1);  SB(bC, 0, 2);  SB(bC, 0, 3);
    SA(aN1, 1, 0); SA(aN1, 1, 1);
    SB(bN1, 1, 0); SB(bN1, 1, 1); SB(bN1, 1, 2); SB(bN1, 1, 3);
    asm volatile("s_waitcnt vmcnt(6)" ::: "memory");
    __builtin_amdgcn_sched_barrier(0);
    __builtin_amdgcn_s_barrier();

    for (int kt = 0; kt < KTILES; ++kt) {
        const int kn = (kt + 2) & (KTILES - 1);   // wrap loads: harmless re-stage
        bf16x8 fA[4], fB0[4], fB1[4];

        // ---- issue ALL fragment reads for tile kt (buffer certified) ------
#pragma unroll
        for (int i = 0; i < 4; ++i)
            fA[i] = *(const bf16x8*)(aC + (mo + i * 16 + fr) * 64 + colK);
#pragma unroll
        for (int j = 0; j < 4; ++j)
            fB0[j] = *(const bf16x8*)(bC + (no + j * 16 + fr) * 64 + colK);
#pragma unroll
        for (int j = 0; j < 4; ++j)
            fB1[j] = *(const bf16x8*)(bC + (no + 64 + j * 16 + fr) * 64 + colK);
        // ---- stage A + B-band0 of tile kt+2 (buf (kt+2)%3: readers done) --
        SA(aN2, kn, 0); SA(aN2, kn, 1); SB(bN2, kn, 0);
        // certify the 8 A/B0 reads (4 B1 reads stay outstanding, DS in-order)
        asm volatile("s_waitcnt lgkmcnt(4)" ::: "memory");
        __builtin_amdgcn_sched_barrier(0);
        __builtin_amdgcn_s_setprio(1);
#pragma unroll
        for (int i = 0; i < 4; ++i)
#pragma unroll
            for (int j = 0; j < 4; ++j)
                acc[i][j] = __builtin_amdgcn_mfma_f32_16x16x32_bf16(
                    fA[i], fB0[j], acc[i][j], 0, 0, 0);
        __builtin_amdgcn_s_setprio(0);
        // certify B1 (covered by the 16-MFMA cluster above)
        asm volatile("s_waitcnt lgkmcnt(0)" ::: "memory");
        __builtin_amdgcn_sched_barrier(0);
        SB(bN2, kn, 1); SB(bN2, kn, 2); SB(bN2, kn, 3);
        __builtin_amdgcn_s_setprio(1);
#pragma unroll
        for (int i = 0; i < 4; ++i)
#pragma unroll
            for (int j = 0; j < 4; ++j)
                acc[i][j + 4] = __builtin_amdgcn_mfma_f32_16x16x32_bf16(
                    fA[i], fB1[j], acc[i][j + 4], 0, 0, 0);
        __builtin_amdgcn_s_setprio(0);
        // certify tile kt+1 (oldest 6 of 12 outstanding); never drains to 0
        asm volatile("s_waitcnt vmcnt(6)" ::: "memory");
        __builtin_amdgcn_sched_barrier(0);
        __builtin_amdgcn_s_barrier();

        // rotate buffers: tile T lives in buf[T % 3]
        u16* tmp;
        tmp = aC; aC = aN1; aN1 = aN2; aN2 = tmp;
        tmp = bC; bC = bN1; bN1 = bN2; bN2 = tmp;
    }

    // ---- epilogue: cross-k-half reduction through LDS ----------------------
    asm volatile("s_waitcnt vmcnt(0)" ::: "memory");
    __builtin_amdgcn_s_barrier();

    // 32 KB region per wq: wq 0..2 -> Bs[wq] (32 KB each), wq 3 -> As (48 KB)
    float* red = (wq == 3) ? (float*)As : (float*)Bs[wq];

    if (kh == 1) {
#pragma unroll
        for (int i = 0; i < 4; ++i)
#pragma unroll
            for (int j = 0; j < 8; ++j)
                *(f32x4*)(red + (i * 8 + j) * 256 + lane * 4) = acc[i][j];
    }
    asm volatile("s_waitcnt lgkmcnt(0)" ::: "memory");
    __builtin_amdgcn_s_barrier();

    if (kh == 0) {
        const int rb = q * 4;
#pragma unroll
        for (int i = 0; i < 4; ++i) {
#pragma unroll
            for (int j = 0; j < 8; ++j) {
                f32x4 other = *(const f32x4*)(red + (i * 8 + j) * 256 + lane * 4);
                int n = bn * 256 + no + j * 16 + fr;
                float bv = bias[n];
#pragma unroll
                for (int r = 0; r < 4; ++r) {
                    int m = bm * 128 + mo + i * 16 + rb + r;
                    C[(size_t)m * N_DIM + n] = acc[i][j][r] + other[r] + bv;
                }
            }
        }
    }
#undef SA
#undef SB
}

extern "C" void kernel_launch(void* const* d_in, const int* in_sizes, int n_in,
                              void* d_out, int out_size, void* d_ws, size_t ws_size,
                              hipStream_t stream) {
    const float* x    = (const float*)d_in[0];  // 2048 x 4096
    const float* mask = (const float*)d_in[1];  // 4096 x 4096
    const float* W    = (const float*)d_in[2];  // 4096 x 4096
    const float* bias = (const float*)d_in[3];  // 4096
    float* out = (float*)d_out;                 // 2048 x 4096

    u16* Bt = (u16*)d_ws;                                   // N*K bf16 = 32 MB
    u16* xb = (u16*)d_ws + (size_t)N_DIM * K_DIM;           // M*K bf16 = 16 MB

    prep_t<<<2048, 256, 0, stream>>>(W, mask, Bt);
    prep_x<<<2048, 256, 0, stream>>>(x, xb);
    gemm8<<<256, 512, 0, stream>>>(xb, Bt, bias, out);
}